// Round 1
// baseline (397.234 us; speedup 1.0000x reference)
//
#include <hip/hip_runtime.h>
#include <math.h>

#define N_EMBED 8192
#define DIM 32
#define NQ 32768              // 32 * 32 * 32 queries
#define KSPLIT 8
#define CHUNK (N_EMBED / KSPLIT)   // 1024 codes per thread

#define OUT0_SIZE 1048576     // 32*32*32*32 z_q output
#define LOSS_OFF  1048576
#define ENT_OFF   1048577
#define IDX_OFF   1048578

// ---------------------------------------------------------------------------
// K0: normalize embedding rows -> ew  (8192 rows of 32 floats)
// ---------------------------------------------------------------------------
__global__ __launch_bounds__(256) void norm_embed_kernel(const float* __restrict__ e,
                                                         float* __restrict__ ew) {
    int k = blockIdx.x * 256 + threadIdx.x;   // 8192 threads
    const float* src = e + k * DIM;
    float v[DIM];
    float ss = 0.f;
#pragma unroll
    for (int d = 0; d < DIM; d += 4) {
        float4 t = *(const float4*)(src + d);
        v[d] = t.x; v[d+1] = t.y; v[d+2] = t.z; v[d+3] = t.w;
        ss += t.x*t.x + t.y*t.y + t.z*t.z + t.w*t.w;
    }
    float inv = 1.f / fmaxf(sqrtf(ss), 1e-12f);
    float* dst = ew + k * DIM;
#pragma unroll
    for (int d = 0; d < DIM; d += 4) {
        float4 t;
        t.x = v[d]*inv; t.y = v[d+1]*inv; t.z = v[d+2]*inv; t.w = v[d+3]*inv;
        *(float4*)(dst + d) = t;
    }
}

// ---------------------------------------------------------------------------
// K1: score. One thread = one (query, chunk-of-K) pair.
// Query in VGPRs, code rows wave-uniform -> scalar loads. Packed-key atomicMax
// combines chunks: high 32 = ordered-float(best dot), low 32 = ~idx
// (max key == max dot, ties -> smallest idx == argmin-first semantics).
// ---------------------------------------------------------------------------
__global__ __launch_bounds__(256) void score_kernel(const float* __restrict__ z,
                                                    const float* __restrict__ ew,
                                                    unsigned long long* __restrict__ keys) {
    int tid = blockIdx.x * 256 + threadIdx.x;      // 0 .. NQ*KSPLIT-1
    int n = tid & (NQ - 1);                        // query id (lane-consecutive)
    int chunk = __builtin_amdgcn_readfirstlane(tid >> 15);  // wave-uniform
    int b  = n >> 10;
    int hw = n & 1023;
    const float* zb = z + b * (DIM * 1024) + hw;   // z[b][d][h][w], stride 1024 per d

    float q[DIM];
    float ss = 0.f;
#pragma unroll
    for (int d = 0; d < DIM; ++d) {                // coalesced: lanes consecutive in hw
        q[d] = zb[d * 1024];
        ss += q[d] * q[d];
    }
    float inv = 1.f / fmaxf(sqrtf(ss), 1e-12f);
#pragma unroll
    for (int d = 0; d < DIM; ++d) q[d] *= inv;

    int k0 = chunk * CHUNK;
    const float* __restrict__ row = ew + k0 * DIM;
    float best = -2.0f;
    int bestk = k0;
#pragma unroll 4
    for (int k = 0; k < CHUNK; ++k) {
        float d0 = 0.f, d1 = 0.f, d2 = 0.f, d3 = 0.f;
#pragma unroll
        for (int d = 0; d < DIM; d += 4) {
            d0 = fmaf(q[d+0], row[d+0], d0);
            d1 = fmaf(q[d+1], row[d+1], d1);
            d2 = fmaf(q[d+2], row[d+2], d2);
            d3 = fmaf(q[d+3], row[d+3], d3);
        }
        float dot = (d0 + d1) + (d2 + d3);
        if (dot > best) { best = dot; bestk = k0 + k; }   // strict > keeps first (lowest k)
        row += DIM;
    }

    unsigned ub = __float_as_uint(best);
    ub = (ub & 0x80000000u) ? ~ub : (ub | 0x80000000u);   // order-preserving encode
    unsigned long long key = ((unsigned long long)ub << 32) | (unsigned)(~bestk);
    atomicMax(keys + n, key);
}

// ---------------------------------------------------------------------------
// K2: finalize per query: idx decode, histogram, z_q gather, straight-through
// output, per-query loss -> wave-reduced atomicAdd.
// ---------------------------------------------------------------------------
__global__ __launch_bounds__(256) void finalize_kernel(const float* __restrict__ z,
                                                       const float* __restrict__ ew,
                                                       const unsigned long long* __restrict__ keys,
                                                       unsigned* __restrict__ usage,
                                                       float* __restrict__ loss_acc,
                                                       float* __restrict__ out) {
    int n = blockIdx.x * 256 + threadIdx.x;        // 0 .. NQ-1
    int b  = n >> 10;
    int hw = n & 1023;
    const float* zb = z + b * (DIM * 1024) + hw;

    float q[DIM];
    float ss = 0.f;
#pragma unroll
    for (int d = 0; d < DIM; ++d) {
        q[d] = zb[d * 1024];
        ss += q[d] * q[d];
    }
    float inv = 1.f / fmaxf(sqrtf(ss), 1e-12f);
#pragma unroll
    for (int d = 0; d < DIM; ++d) q[d] *= inv;

    unsigned long long key = keys[n];
    int idx = (int)(~(unsigned)(key & 0xFFFFFFFFull));   // undo ~bestk

    atomicAdd(&usage[idx], 1u);

    const float* erow = ew + idx * DIM;
    float lsum = 0.f;
    float* outb = out + b * (DIM * 1024) + hw;
#pragma unroll
    for (int d = 0; d < DIM; ++d) {
        float zq = erow[d];
        float diff = zq - q[d];
        lsum += diff * diff;
        outb[d * 1024] = q[d] + (zq - q[d]);     // faithful to zn + sg(z_q - zn)
    }
    out[IDX_OFF + n] = (float)idx;

    // wave-level reduction of lsum, one atomic per wave
#pragma unroll
    for (int off = 32; off > 0; off >>= 1)
        lsum += __shfl_down(lsum, off, 64);
    if ((threadIdx.x & 63) == 0)
        atomicAdd(loss_acc, lsum);
}

// ---------------------------------------------------------------------------
// K3: entropy over histogram + loss scalar. Single block.
// ---------------------------------------------------------------------------
__global__ __launch_bounds__(256) void scalars_kernel(const unsigned* __restrict__ usage,
                                                      const float* __restrict__ loss_acc,
                                                      float* __restrict__ out) {
    __shared__ double sm[256];
    int t = threadIdx.x;
    double local = 0.0;
    // denom = sum(usage + 1e-4) = 32768 + 8192e-4 (sum(usage) == NQ always)
    const float denom = 32768.8192f;
    for (int k = t; k < N_EMBED; k += 256) {
        float p = ((float)usage[k] + 1e-4f) / denom;
        local += (double)(-(p * logf(p)));
    }
    sm[t] = local;
    __syncthreads();
    for (int s = 128; s > 0; s >>= 1) {
        if (t < s) sm[t] += sm[t + s];
        __syncthreads();
    }
    if (t == 0) {
        out[LOSS_OFF] = (float)(1.25 * (double)loss_acc[0] / 32768.0);  // (beta + 1) * mean
        out[ENT_OFF]  = (float)sm[0];
    }
}

// ---------------------------------------------------------------------------
extern "C" void kernel_launch(void* const* d_in, const int* in_sizes, int n_in,
                              void* d_out, int out_size, void* d_ws, size_t ws_size,
                              hipStream_t stream) {
    const float* z   = (const float*)d_in[0];   // (32, 32, 32, 32) bchw
    const float* emb = (const float*)d_in[1];   // (8192, 32)
    float* out = (float*)d_out;

    char* ws = (char*)d_ws;
    float* ew                   = (float*)ws;                               // 1 MiB
    unsigned long long* keys    = (unsigned long long*)(ws + (1 << 20));    // 256 KiB
    unsigned* usage             = (unsigned*)(ws + (1 << 20) + NQ * 8);     // 32 KiB
    float* loss_acc             = (float*)(ws + (1 << 20) + NQ * 8 + N_EMBED * 4);

    // zero keys + usage + loss (contiguous region)
    hipMemsetAsync(keys, 0, (size_t)NQ * 8 + N_EMBED * 4 + 4, stream);

    norm_embed_kernel<<<N_EMBED / 256, 256, 0, stream>>>(emb, ew);
    score_kernel<<<(NQ * KSPLIT) / 256, 256, 0, stream>>>(z, ew, keys);
    finalize_kernel<<<NQ / 256, 256, 0, stream>>>(z, ew, keys, usage, loss_acc, out);
    scalars_kernel<<<1, 256, 0, stream>>>(usage, loss_acc, out);
}

// Round 2
// 301.032 us; speedup vs baseline: 1.3196x; 1.3196x over previous
//
#include <hip/hip_runtime.h>
#include <math.h>

#define N_EMBED 8192
#define DIM 32
#define NQ 32768              // 32 * 32 * 32 queries
#define QPT 2                 // queries per thread
#define QPB 512               // queries per block (256 threads * QPT)
#define NQG (NQ / QPB)        // 64 query groups
#define KSPLIT 16
#define CHUNK (N_EMBED / KSPLIT)   // 512 codebook rows per block
#define TILE 128              // rows per LDS tile (16 KB)
#define NT (CHUNK / TILE)     // 4 tiles

#define LOSS_OFF  1048576
#define ENT_OFF   1048577
#define IDX_OFF   1048578

// ---------------------------------------------------------------------------
// K0: normalize embedding rows -> ew  (8192 rows of 32 floats)
// ---------------------------------------------------------------------------
__global__ __launch_bounds__(256) void norm_embed_kernel(const float* __restrict__ e,
                                                         float* __restrict__ ew) {
    int k = blockIdx.x * 256 + threadIdx.x;   // 8192 threads
    const float* src = e + k * DIM;
    float v[DIM];
    float ss = 0.f;
#pragma unroll
    for (int d = 0; d < DIM; d += 4) {
        float4 t = *(const float4*)(src + d);
        v[d] = t.x; v[d+1] = t.y; v[d+2] = t.z; v[d+3] = t.w;
        ss += t.x*t.x + t.y*t.y + t.z*t.z + t.w*t.w;
    }
    float inv = 1.f / fmaxf(sqrtf(ss), 1e-12f);
    float* dst = ew + k * DIM;
#pragma unroll
    for (int d = 0; d < DIM; d += 4) {
        float4 t;
        t.x = v[d]*inv; t.y = v[d+1]*inv; t.z = v[d+2]*inv; t.w = v[d+3]*inv;
        *(float4*)(dst + d) = t;
    }
}

// ---------------------------------------------------------------------------
// K1: score. Block = 256 threads, each thread holds TWO normalized queries in
// VGPRs (64 regs). Block iterates over a 512-row K-chunk staged through LDS in
// 128-row double-buffered tiles. All lanes read the same LDS row (broadcast,
// conflict-free). Chained fp32 FMA accumulator per query; strict > keeps the
// first (lowest-k) min. Cross-chunk combine via packed-key atomicMax:
// high 32 = ordered-float(dot), low 32 = ~k  (ties -> smallest k).
// __launch_bounds__(256,4): cap VGPRs at 128 so q[] is NOT spilled (R1 bug:
// VGPR_Count=28 -> compiler spilled the query vector, VALUBusy 46%).
// ---------------------------------------------------------------------------
__global__ __launch_bounds__(256, 4) void score_kernel(const float* __restrict__ z,
                                                       const float* __restrict__ ew,
                                                       unsigned long long* __restrict__ keys) {
    __shared__ float lds[2][TILE * DIM];   // 2 x 16 KB

    const int t = threadIdx.x;
    const int qg = blockIdx.x & (NQG - 1);     // query group, 0..63
    const int chunk = blockIdx.x >> 6;         // K chunk, 0..KSPLIT-1

    // ---- load + normalize 2 queries into registers ----
    const int n0 = qg * QPB + t;
    const int n1 = n0 + 256;
    const float* z0 = z + (n0 >> 10) * (DIM * 1024) + (n0 & 1023);  // [b][d][h][w]
    const float* z1 = z + (n1 >> 10) * (DIM * 1024) + (n1 & 1023);

    float q0[DIM], q1[DIM];
    float ss0 = 0.f, ss1 = 0.f;
#pragma unroll
    for (int d = 0; d < DIM; ++d) { q0[d] = z0[d * 1024]; ss0 = fmaf(q0[d], q0[d], ss0); }
#pragma unroll
    for (int d = 0; d < DIM; ++d) { q1[d] = z1[d * 1024]; ss1 = fmaf(q1[d], q1[d], ss1); }
    const float inv0 = 1.f / fmaxf(sqrtf(ss0), 1e-12f);
    const float inv1 = 1.f / fmaxf(sqrtf(ss1), 1e-12f);
#pragma unroll
    for (int d = 0; d < DIM; ++d) { q0[d] *= inv0; q1[d] *= inv1; }

    // ---- stage helper: copy one 16 KB tile (128 rows) global -> LDS ----
    auto stage = [&](int buf, int tileIdx) {
        const float4* src = (const float4*)(ew + (chunk * CHUNK + tileIdx * TILE) * DIM);
        float4* dst = (float4*)&lds[buf][0];
#pragma unroll
        for (int j = 0; j < 4; ++j)
            dst[t + j * 256] = src[t + j * 256];   // coalesced, 1024 float4 total
    };

    float best0 = -2.0f, best1 = -2.0f;
    int bk0 = 0, bk1 = 0;

    stage(0, 0);
    __syncthreads();

    for (int tt = 0; tt < NT; ++tt) {
        const int cur = tt & 1;
        if (tt + 1 < NT) stage(cur ^ 1, tt + 1);   // overwrites buffer freed by last barrier

        const int kbase = chunk * CHUNK + tt * TILE;
        const float* __restrict__ buf = &lds[cur][0];
#pragma unroll 2
        for (int r = 0; r < TILE; ++r) {
            const float* row = buf + r * DIM;
            float a0, a1;
#pragma unroll
            for (int d = 0; d < DIM; d += 4) {
                float4 rv = *(const float4*)(row + d);
                if (d == 0) { a0 = q0[0] * rv.x; a1 = q1[0] * rv.x; }
                else        { a0 = fmaf(q0[d], rv.x, a0); a1 = fmaf(q1[d], rv.x, a1); }
                a0 = fmaf(q0[d+1], rv.y, a0);  a1 = fmaf(q1[d+1], rv.y, a1);
                a0 = fmaf(q0[d+2], rv.z, a0);  a1 = fmaf(q1[d+2], rv.z, a1);
                a0 = fmaf(q0[d+3], rv.w, a0);  a1 = fmaf(q1[d+3], rv.w, a1);
            }
            const int kk = kbase + r;
            if (a0 > best0) { best0 = a0; bk0 = kk; }
            if (a1 > best1) { best1 = a1; bk1 = kk; }
        }
        __syncthreads();
    }

    // ---- order-preserving float encode + packed-key atomicMax ----
    unsigned u0 = __float_as_uint(best0);
    u0 = (u0 & 0x80000000u) ? ~u0 : (u0 | 0x80000000u);
    unsigned u1 = __float_as_uint(best1);
    u1 = (u1 & 0x80000000u) ? ~u1 : (u1 | 0x80000000u);
    atomicMax(keys + n0, ((unsigned long long)u0 << 32) | (unsigned)(~bk0));
    atomicMax(keys + n1, ((unsigned long long)u1 << 32) | (unsigned)(~bk1));
}

// ---------------------------------------------------------------------------
// K2: finalize per query: idx decode, histogram, z_q gather, straight-through
// output, per-query loss -> wave-reduced atomicAdd.
// ---------------------------------------------------------------------------
__global__ __launch_bounds__(256, 4) void finalize_kernel(const float* __restrict__ z,
                                                          const float* __restrict__ ew,
                                                          const unsigned long long* __restrict__ keys,
                                                          unsigned* __restrict__ usage,
                                                          float* __restrict__ loss_acc,
                                                          float* __restrict__ out) {
    int n = blockIdx.x * 256 + threadIdx.x;        // 0 .. NQ-1
    int b  = n >> 10;
    int hw = n & 1023;
    const float* zb = z + b * (DIM * 1024) + hw;

    float q[DIM];
    float ss = 0.f;
#pragma unroll
    for (int d = 0; d < DIM; ++d) {
        q[d] = zb[d * 1024];
        ss = fmaf(q[d], q[d], ss);
    }
    float inv = 1.f / fmaxf(sqrtf(ss), 1e-12f);
#pragma unroll
    for (int d = 0; d < DIM; ++d) q[d] *= inv;

    unsigned long long key = keys[n];
    int idx = (int)(~(unsigned)(key & 0xFFFFFFFFull));   // undo ~bestk

    atomicAdd(&usage[idx], 1u);

    const float* erow = ew + idx * DIM;
    float lsum = 0.f;
    float* outb = out + b * (DIM * 1024) + hw;
#pragma unroll
    for (int d = 0; d < DIM; ++d) {
        float zq = erow[d];
        float diff = zq - q[d];
        lsum = fmaf(diff, diff, lsum);
        outb[d * 1024] = q[d] + (zq - q[d]);     // faithful to zn + sg(z_q - zn)
    }
    out[IDX_OFF + n] = (float)idx;

    // wave-level reduction of lsum, one atomic per wave
#pragma unroll
    for (int off = 32; off > 0; off >>= 1)
        lsum += __shfl_down(lsum, off, 64);
    if ((threadIdx.x & 63) == 0)
        atomicAdd(loss_acc, lsum);
}

// ---------------------------------------------------------------------------
// K3: entropy over histogram + loss scalar. Single block.
// ---------------------------------------------------------------------------
__global__ __launch_bounds__(256) void scalars_kernel(const unsigned* __restrict__ usage,
                                                      const float* __restrict__ loss_acc,
                                                      float* __restrict__ out) {
    __shared__ double sm[256];
    int t = threadIdx.x;
    double local = 0.0;
    // denom = sum(usage + 1e-4) = 32768 + 8192e-4 (sum(usage) == NQ always)
    const float denom = 32768.8192f;
    for (int k = t; k < N_EMBED; k += 256) {
        float p = ((float)usage[k] + 1e-4f) / denom;
        local += (double)(-(p * logf(p)));
    }
    sm[t] = local;
    __syncthreads();
    for (int s = 128; s > 0; s >>= 1) {
        if (t < s) sm[t] += sm[t + s];
        __syncthreads();
    }
    if (t == 0) {
        out[LOSS_OFF] = (float)(1.25 * (double)loss_acc[0] / 32768.0);  // (beta+1)*mean
        out[ENT_OFF]  = (float)sm[0];
    }
}

// ---------------------------------------------------------------------------
extern "C" void kernel_launch(void* const* d_in, const int* in_sizes, int n_in,
                              void* d_out, int out_size, void* d_ws, size_t ws_size,
                              hipStream_t stream) {
    const float* z   = (const float*)d_in[0];   // (32, 32, 32, 32) bchw
    const float* emb = (const float*)d_in[1];   // (8192, 32)
    float* out = (float*)d_out;

    char* ws = (char*)d_ws;
    float* ew                   = (float*)ws;                               // 1 MiB
    unsigned long long* keys    = (unsigned long long*)(ws + (1 << 20));    // 256 KiB
    unsigned* usage             = (unsigned*)(ws + (1 << 20) + NQ * 8);     // 32 KiB
    float* loss_acc             = (float*)(ws + (1 << 20) + NQ * 8 + N_EMBED * 4);

    // zero keys + usage + loss (contiguous region)
    hipMemsetAsync(keys, 0, (size_t)NQ * 8 + N_EMBED * 4 + 4, stream);

    norm_embed_kernel<<<N_EMBED / 256, 256, 0, stream>>>(emb, ew);
    score_kernel<<<NQG * KSPLIT, 256, 0, stream>>>(z, ew, keys);
    finalize_kernel<<<NQ / 256, 256, 0, stream>>>(z, ew, keys, usage, loss_acc, out);
    scalars_kernel<<<1, 256, 0, stream>>>(usage, loss_acc, out);
}

// Round 3
// 166.076 us; speedup vs baseline: 2.3919x; 1.8126x over previous
//
#include <hip/hip_runtime.h>
#include <math.h>

#define N_EMBED 8192
#define DIM 32
#define NQ 32768              // 32 * 32 * 32 queries

#define TILE 128              // codes staged per LDS tile
#define LSTRIDE 130           // plane stride in 16B chunks (+2 pad: quads offset 8 words)
#define KCHUNK 1024           // codes per block
#define NTILES (KCHUNK / TILE)
#define QPB 512               // queries per block (8 waves * 64)
#define NQG (NQ / QPB)        // 64
#define KSPL (N_EMBED / KCHUNK)  // 8

#define LOSS_OFF  1048576
#define ENT_OFF   1048577
#define IDX_OFF   1048578

typedef __attribute__((ext_vector_type(8))) short short8;
typedef __attribute__((ext_vector_type(4))) float floatx4;

__device__ __forceinline__ unsigned short bf16_rne(float x) {
    unsigned u = __float_as_uint(x);
    unsigned r = u + 0x7FFFu + ((u >> 16) & 1u);
    return (unsigned short)(r >> 16);
}
__device__ __forceinline__ float bf16_f(unsigned short h) {
    return __uint_as_float(((unsigned)h) << 16);
}

// ---------------------------------------------------------------------------
// K0: normalize codes -> ew (fp32, for finalize) AND emit exact 3-way bf16
// split (h,m,l) in MFMA-B-fragment-friendly layout:
//   esplit chunk layout: plane p = s*4 + b8 (s=0:h,1:m,2:l; b8 = k/8),
//   chunk index = p*8192 + code; each chunk = 8 bf16 = 16 B.
// ---------------------------------------------------------------------------
__global__ __launch_bounds__(256) void prep_codes(const float* __restrict__ e,
                                                  float* __restrict__ ew,
                                                  unsigned short* __restrict__ esplit) {
    int k = blockIdx.x * 256 + threadIdx.x;   // 8192 threads
    const float* src = e + k * DIM;
    float v[DIM];
    float ss = 0.f;
#pragma unroll
    for (int d = 0; d < DIM; d += 4) {
        float4 t = *(const float4*)(src + d);
        v[d] = t.x; v[d+1] = t.y; v[d+2] = t.z; v[d+3] = t.w;
        ss += t.x*t.x + t.y*t.y + t.z*t.z + t.w*t.w;
    }
    float inv = 1.f / fmaxf(sqrtf(ss), 1e-12f);
#pragma unroll
    for (int d = 0; d < DIM; ++d) v[d] *= inv;

    float* dst = ew + k * DIM;
#pragma unroll
    for (int d = 0; d < DIM; d += 4) {
        float4 t; t.x = v[d]; t.y = v[d+1]; t.z = v[d+2]; t.w = v[d+3];
        *(float4*)(dst + d) = t;
    }

    short8* ep = (short8*)esplit;
#pragma unroll
    for (int b8 = 0; b8 < 4; ++b8) {
        short8 h8, m8, l8;
#pragma unroll
        for (int j = 0; j < 8; ++j) {
            float x = v[b8 * 8 + j];
            unsigned short h = bf16_rne(x);
            float r1 = x - bf16_f(h);
            unsigned short m = bf16_rne(r1);
            float r2 = r1 - bf16_f(m);
            unsigned short l = bf16_rne(r2);
            h8[j] = (short)h; m8[j] = (short)m; l8[j] = (short)l;
        }
        ep[(0 * 4 + b8) * N_EMBED + k] = h8;
        ep[(1 * 4 + b8) * N_EMBED + k] = m8;
        ep[(2 * 4 + b8) * N_EMBED + k] = l8;
    }
}

// ---------------------------------------------------------------------------
// K1: score via exact split-bf16 MFMA. Block = 512 threads (8 waves); wave w
// owns 64 queries (4 tiles of 16 rows); block scans KCHUNK=1024 codes staged
// through LDS in double-buffered 128-code tiles. Dot = 6-term MFMA chain
// (hh+hm+mh+hl+lh+mm), error ~1e-8 << fp32 noise. Per-lane argmax state per
// C-row; quad shuffle-reduce; packed-key atomicMax across blocks (ties ->
// smallest k, matching argmin-first).
// ---------------------------------------------------------------------------
__global__ __launch_bounds__(512, 2) void score_mfma(const float* __restrict__ z,
                                                     const unsigned short* __restrict__ esplit,
                                                     unsigned long long* __restrict__ keys) {
    __shared__ short8 lds[2][12 * LSTRIDE];   // 49,920 B

    const int t = threadIdx.x;
    const int lane = t & 63;
    const int w = t >> 6;           // wave 0..7
    const int quad = lane >> 4;     // k-block / C-row group
    const int lc = lane & 15;       // A-row / B-col / C-col
    const int qg = blockIdx.x & (NQG - 1);
    const int kc = blockIdx.x >> 6;        // 0..KSPL-1
    const int kbase = kc * KCHUNK;
    const int qbase = qg * QPB + w * 64;

    // ---- build A fragments: 4 q-tiles, on-the-fly normalize + 3-way split ----
    short8 ah[4], am[4], al[4];
#pragma unroll
    for (int qt = 0; qt < 4; ++qt) {
        int q = qbase + qt * 16 + lc;
        const float* zp = z + (q >> 10) * (DIM * 1024) + (q & 1023);
        float x[8];
        float ss = 0.f;
#pragma unroll
        for (int j = 0; j < 8; ++j) {
            x[j] = zp[(quad * 8 + j) * 1024];
            ss = fmaf(x[j], x[j], ss);
        }
        ss += __shfl_xor(ss, 16, 64);     // lanes sharing row lc: quads 0..3
        ss += __shfl_xor(ss, 32, 64);
        float inv = 1.f / fmaxf(sqrtf(ss), 1e-12f);
        short8 h8, m8, l8;
#pragma unroll
        for (int j = 0; j < 8; ++j) {
            float xx = x[j] * inv;
            unsigned short h = bf16_rne(xx);
            float r1 = xx - bf16_f(h);
            unsigned short m = bf16_rne(r1);
            float r2 = r1 - bf16_f(m);
            unsigned short l = bf16_rne(r2);
            h8[j] = (short)h; m8[j] = (short)m; l8[j] = (short)l;
        }
        ah[qt] = h8; am[qt] = m8; al[qt] = l8;
    }

    float best[16];
    int bk[16];
#pragma unroll
    for (int i = 0; i < 16; ++i) { best[i] = -2.0f; bk[i] = 0; }

    const short8* gsp = (const short8*)esplit;

    // preload tile 0: 12 planes x 128 chunks = 1536 chunks / 512 threads = 3 each
#pragma unroll
    for (int j = 0; j < 3; ++j) {
        int c = t + j * 512; int p = c >> 7, i = c & 127;
        lds[0][p * LSTRIDE + i] = gsp[p * N_EMBED + kbase + i];
    }
    __syncthreads();

    for (int kt = 0; kt < NTILES; ++kt) {
        short8 st[3];
        if (kt + 1 < NTILES) {
#pragma unroll
            for (int j = 0; j < 3; ++j) {
                int c = t + j * 512; int p = c >> 7, i = c & 127;
                st[j] = gsp[p * N_EMBED + kbase + (kt + 1) * TILE + i];
            }
        }
        const short8* __restrict__ buf = lds[kt & 1];
        for (int ct = 0; ct < TILE / 16; ++ct) {
            short8 bh = buf[(0 * 4 + quad) * LSTRIDE + ct * 16 + lc];
            short8 bm = buf[(1 * 4 + quad) * LSTRIDE + ct * 16 + lc];
            short8 bl = buf[(2 * 4 + quad) * LSTRIDE + ct * 16 + lc];
            const int kk = kbase + kt * TILE + ct * 16 + lc;
#pragma unroll
            for (int qt = 0; qt < 4; ++qt) {
                floatx4 acc = {0.f, 0.f, 0.f, 0.f};
                acc = __builtin_amdgcn_mfma_f32_16x16x32_bf16(am[qt], bm, acc, 0, 0, 0);
                acc = __builtin_amdgcn_mfma_f32_16x16x32_bf16(al[qt], bh, acc, 0, 0, 0);
                acc = __builtin_amdgcn_mfma_f32_16x16x32_bf16(ah[qt], bl, acc, 0, 0, 0);
                acc = __builtin_amdgcn_mfma_f32_16x16x32_bf16(am[qt], bh, acc, 0, 0, 0);
                acc = __builtin_amdgcn_mfma_f32_16x16x32_bf16(ah[qt], bm, acc, 0, 0, 0);
                acc = __builtin_amdgcn_mfma_f32_16x16x32_bf16(ah[qt], bh, acc, 0, 0, 0);
#pragma unroll
                for (int r = 0; r < 4; ++r) {
                    if (acc[r] > best[qt * 4 + r]) { best[qt * 4 + r] = acc[r]; bk[qt * 4 + r] = kk; }
                }
            }
        }
        __syncthreads();
        if (kt + 1 < NTILES) {
#pragma unroll
            for (int j = 0; j < 3; ++j) {
                int c = t + j * 512; int p = c >> 7, i = c & 127;
                lds[(kt + 1) & 1][p * LSTRIDE + i] = st[j];
            }
        }
        __syncthreads();
    }

    // ---- epilogue: pack (dot,k) keys, reduce over the quad's 16 cols ----
#pragma unroll
    for (int i = 0; i < 16; ++i) {
        unsigned ub = __float_as_uint(best[i]);
        ub = (ub & 0x80000000u) ? ~ub : (ub | 0x80000000u);
        unsigned long long key = ((unsigned long long)ub << 32) | (unsigned)(~bk[i]);
#pragma unroll
        for (int msk = 1; msk <= 8; msk <<= 1) {
            unsigned long long o = __shfl_xor(key, msk, 64);
            key = (o > key) ? o : key;
        }
        if (lc == 0) {
            int qt = i >> 2, r = i & 3;
            int q = qbase + qt * 16 + quad * 4 + r;   // C-row = quad*4+reg
            atomicMax(keys + q, key);
        }
    }
}

// ---------------------------------------------------------------------------
// K2: finalize per query: idx decode, histogram, z_q gather, straight-through
// output, per-query loss -> wave-reduced atomicAdd.
// ---------------------------------------------------------------------------
__global__ __launch_bounds__(256, 4) void finalize_kernel(const float* __restrict__ z,
                                                          const float* __restrict__ ew,
                                                          const unsigned long long* __restrict__ keys,
                                                          unsigned* __restrict__ usage,
                                                          float* __restrict__ loss_acc,
                                                          float* __restrict__ out) {
    int n = blockIdx.x * 256 + threadIdx.x;        // 0 .. NQ-1
    int b  = n >> 10;
    int hw = n & 1023;
    const float* zb = z + b * (DIM * 1024) + hw;

    float q[DIM];
    float ss = 0.f;
#pragma unroll
    for (int d = 0; d < DIM; ++d) {
        q[d] = zb[d * 1024];
        ss = fmaf(q[d], q[d], ss);
    }
    float inv = 1.f / fmaxf(sqrtf(ss), 1e-12f);
#pragma unroll
    for (int d = 0; d < DIM; ++d) q[d] *= inv;

    unsigned long long key = keys[n];
    int idx = (int)(~(unsigned)(key & 0xFFFFFFFFull));

    atomicAdd(&usage[idx], 1u);

    const float* erow = ew + idx * DIM;
    float lsum = 0.f;
    float* outb = out + b * (DIM * 1024) + hw;
#pragma unroll
    for (int d = 0; d < DIM; ++d) {
        float zq = erow[d];
        float diff = zq - q[d];
        lsum = fmaf(diff, diff, lsum);
        outb[d * 1024] = q[d] + (zq - q[d]);     // faithful to zn + sg(z_q - zn)
    }
    out[IDX_OFF + n] = (float)idx;

#pragma unroll
    for (int off = 32; off > 0; off >>= 1)
        lsum += __shfl_down(lsum, off, 64);
    if ((threadIdx.x & 63) == 0)
        atomicAdd(loss_acc, lsum);
}

// ---------------------------------------------------------------------------
// K3: entropy over histogram + loss scalar. Single block.
// ---------------------------------------------------------------------------
__global__ __launch_bounds__(256) void scalars_kernel(const unsigned* __restrict__ usage,
                                                      const float* __restrict__ loss_acc,
                                                      float* __restrict__ out) {
    __shared__ double sm[256];
    int t = threadIdx.x;
    double local = 0.0;
    const float denom = 32768.8192f;   // sum(usage)+K*eps, sum(usage)==NQ always
    for (int k = t; k < N_EMBED; k += 256) {
        float p = ((float)usage[k] + 1e-4f) / denom;
        local += (double)(-(p * logf(p)));
    }
    sm[t] = local;
    __syncthreads();
    for (int s = 128; s > 0; s >>= 1) {
        if (t < s) sm[t] += sm[t + s];
        __syncthreads();
    }
    if (t == 0) {
        out[LOSS_OFF] = (float)(1.25 * (double)loss_acc[0] / 32768.0);
        out[ENT_OFF]  = (float)sm[0];
    }
}

// ---------------------------------------------------------------------------
extern "C" void kernel_launch(void* const* d_in, const int* in_sizes, int n_in,
                              void* d_out, int out_size, void* d_ws, size_t ws_size,
                              hipStream_t stream) {
    const float* z   = (const float*)d_in[0];   // (32, 32, 32, 32) bchw
    const float* emb = (const float*)d_in[1];   // (8192, 32)
    float* out = (float*)d_out;

    char* ws = (char*)d_ws;
    float* ew                = (float*)ws;                                  // 1 MiB
    unsigned long long* keys = (unsigned long long*)(ws + (1 << 20));       // 256 KiB
    unsigned* usage          = (unsigned*)(ws + (1 << 20) + NQ * 8);        // 32 KiB
    float* loss_acc          = (float*)(ws + (1 << 20) + NQ * 8 + N_EMBED * 4);
    unsigned short* esplit   = (unsigned short*)(ws + (1 << 20) + (1 << 19)); // 1.5 MiB @ 1.5 MiB

    hipMemsetAsync(keys, 0, (size_t)NQ * 8 + N_EMBED * 4 + 8, stream);

    prep_codes<<<N_EMBED / 256, 256, 0, stream>>>(emb, ew, esplit);
    score_mfma<<<NQG * KSPL, 512, 0, stream>>>(z, esplit, keys);
    finalize_kernel<<<NQ / 256, 256, 0, stream>>>(z, ew, keys, usage, loss_acc, out);
    scalars_kernel<<<1, 256, 0, stream>>>(usage, loss_acc, out);
}

// Round 5
// 152.005 us; speedup vs baseline: 2.6133x; 1.0926x over previous
//
#include <hip/hip_runtime.h>
#include <math.h>

#define N_EMBED 8192
#define DIM 32
#define NQ 32768              // 32*32*32 queries

#define QPB 256               // queries per block (4 waves x 64)
#define NQG (NQ / QPB)        // 128 query groups
#define KSPL 8
#define KCHUNK (N_EMBED / KSPL)   // 1024 codes per block
#define TILE 128              // codes per LDS tile
#define NTILES (KCHUNK / TILE)    // 8
#define NPLANE 8              // p = s*4 + b8 ; s=0: h, s=1: m' = (x-h)*4096
#define LSTRIDE 130           // chunks per plane in LDS (+2 pad: rotate quads 8 banks)

#define LOSS_OFF  1048576
#define ENT_OFF   1048577
#define IDX_OFF   1048578

typedef __attribute__((ext_vector_type(8))) _Float16 half8;
typedef __attribute__((ext_vector_type(4))) float floatx4;

// ---------------------------------------------------------------------------
// K0: per-code normalize + exact 2-way fp16 split + inv_norm table + zero the
// side accumulators. ONE THREAD PER CODE (grid = 8192/256 = 32 blocks; R4's
// fatal bug was launching 1/4 of this grid).
//   esplit chunk layout: plane p = s*4 + part (s=0: h=fp16(x); s=1:
//   m'=fp16((x-h)*4096)); chunk index = p*8192 + code; chunk = 8 halves = 16 B.
// m scaled 2^12 so the m-plane stays fp16-normal.
// ---------------------------------------------------------------------------
__global__ __launch_bounds__(256) void prep_kernel(const float* __restrict__ e,
                                                   half8* __restrict__ esplit,
                                                   float* __restrict__ inv_norm,
                                                   unsigned* __restrict__ usage,
                                                   float* __restrict__ loss_acc,
                                                   unsigned* __restrict__ done_ctr) {
    int k = blockIdx.x * 256 + threadIdx.x;    // 0..8191
    const float4* src = (const float4*)(e + k * DIM);
    float v[DIM];
    float ss = 0.f;
#pragma unroll
    for (int i = 0; i < 8; ++i) {
        float4 t = src[i];
        v[i*4+0] = t.x; v[i*4+1] = t.y; v[i*4+2] = t.z; v[i*4+3] = t.w;
        ss += t.x*t.x + t.y*t.y + t.z*t.z + t.w*t.w;
    }
    float inv = 1.f / fmaxf(sqrtf(ss), 1e-12f);
    inv_norm[k] = inv;
    usage[k] = 0u;
    if (k == 0) { loss_acc[0] = 0.f; done_ctr[0] = 0u; }

#pragma unroll
    for (int part = 0; part < 4; ++part) {
        half8 h8, m8;
#pragma unroll
        for (int j = 0; j < 8; ++j) {
            float xx = v[part * 8 + j] * inv;
            _Float16 h = (_Float16)xx;                          // RNE
            _Float16 m = (_Float16)((xx - (float)h) * 4096.0f); // exact residual, scaled
            h8[j] = h; m8[j] = m;
        }
        esplit[(0 * 4 + part) * N_EMBED + k] = h8;
        esplit[(1 * 4 + part) * N_EMBED + k] = m8;
    }
}

// ---------------------------------------------------------------------------
// K1: candidate filter via split-fp16 MFMA, 3 terms: dot = hh + 2^-12(hm'+m'h).
// Block = 256 threads (4 waves); wave owns 64 queries; block (qg,kc) scans its
// 1024-code chunk double-buffered through LDS. Per-lane argmax per C-row;
// 16-col shfl reduce; TOP-1 PER (QUERY, CHUNK) stored to keys8[kc*NQ+q]
// (plain store — block owns the slot; no atomics, no zeroing needed).
// finalize exact-rescores the 8 chunk winners, so fp16 noise can only matter
// for same-chunk near-ties (negligible: split error ~7e-9 rms < fp32 accum
// noise that R1-R3 passed with).
// ---------------------------------------------------------------------------
__global__ __launch_bounds__(256, 4) void score_kernel(const float* __restrict__ z,
                                                       const half8* __restrict__ esplit,
                                                       unsigned long long* __restrict__ keys8) {
    __shared__ half8 lds[2][NPLANE * LSTRIDE];   // 33,280 B

    const int t = threadIdx.x;
    const int lane = t & 63;
    const int w = t >> 6;            // wave 0..3
    const int quad = lane >> 4;      // k-group (b8) / C-row group
    const int lc = lane & 15;        // A-row / B-col / C-col
    const int qg = blockIdx.x & (NQG - 1);
    const int kc = blockIdx.x >> 7;          // 0..KSPL-1
    const int kbase = kc * KCHUNK;
    const int qbase = qg * QPB + w * 64;

    // ---- A fragments: 4 q-tiles, on-the-fly normalize + fp16 split ----
    half8 ah[4], am[4];
#pragma unroll
    for (int qt = 0; qt < 4; ++qt) {
        int q = qbase + qt * 16 + lc;
        const float* zp = z + (q >> 10) * (DIM * 1024) + (q & 1023);
        float x[8];
        float ss = 0.f;
#pragma unroll
        for (int j = 0; j < 8; ++j) {
            x[j] = zp[(quad * 8 + j) * 1024];
            ss = fmaf(x[j], x[j], ss);
        }
        ss += __shfl_xor(ss, 16, 64);   // combine the 4 quads holding this query
        ss += __shfl_xor(ss, 32, 64);
        float inv = 1.f / fmaxf(sqrtf(ss), 1e-12f);
#pragma unroll
        for (int j = 0; j < 8; ++j) {
            float xx = x[j] * inv;
            _Float16 h = (_Float16)xx;
            _Float16 m = (_Float16)((xx - (float)h) * 4096.0f);
            ah[qt][j] = h; am[qt][j] = m;
        }
    }

    float best[16];
    int bk[16];
#pragma unroll
    for (int i = 0; i < 16; ++i) { best[i] = -2.0f; bk[i] = 0; }

    const floatx4 z4 = {0.f, 0.f, 0.f, 0.f};

    // ---- staging: 8 planes x 128 chunks = 1024 chunks / 256 threads = 4 ea ----
#pragma unroll
    for (int j = 0; j < 4; ++j) {
        int c = t + j * 256; int p = c >> 7, i = c & 127;
        lds[0][p * LSTRIDE + i] = esplit[p * N_EMBED + kbase + i];
    }
    __syncthreads();

    for (int kt = 0; kt < NTILES; ++kt) {
        half8 st[4];
        if (kt + 1 < NTILES) {
#pragma unroll
            for (int j = 0; j < 4; ++j) {
                int c = t + j * 256; int p = c >> 7, i = c & 127;
                st[j] = esplit[p * N_EMBED + kbase + (kt + 1) * TILE + i];
            }
        }
        const half8* __restrict__ buf = lds[kt & 1];
#pragma unroll 2
        for (int ct = 0; ct < TILE / 16; ++ct) {
            half8 bh = buf[(0 * 4 + quad) * LSTRIDE + ct * 16 + lc];
            half8 bm = buf[(1 * 4 + quad) * LSTRIDE + ct * 16 + lc];
            const int kk = kbase + kt * TILE + ct * 16 + lc;
#pragma unroll
            for (int qt = 0; qt < 4; ++qt) {
                floatx4 a0 = __builtin_amdgcn_mfma_f32_16x16x32_f16(ah[qt], bh, z4, 0, 0, 0);
                floatx4 a1 = __builtin_amdgcn_mfma_f32_16x16x32_f16(ah[qt], bm, z4, 0, 0, 0);
                a1 = __builtin_amdgcn_mfma_f32_16x16x32_f16(am[qt], bh, a1, 0, 0, 0);
#pragma unroll
                for (int r = 0; r < 4; ++r) {
                    float d = fmaf(a1[r], 0x1p-12f, a0[r]);
                    if (d > best[qt * 4 + r]) { best[qt * 4 + r] = d; bk[qt * 4 + r] = kk; }
                }
            }
        }
        __syncthreads();
        if (kt + 1 < NTILES) {
#pragma unroll
            for (int j = 0; j < 4; ++j) {
                int c = t + j * 256; int p = c >> 7, i = c & 127;
                lds[(kt + 1) & 1][p * LSTRIDE + i] = st[j];
            }
            __syncthreads();
        }
    }

    // ---- epilogue: pack (dot,k), reduce over 16 cols, plain store per row ----
#pragma unroll
    for (int i = 0; i < 16; ++i) {
        unsigned ub = __float_as_uint(best[i]);
        ub = (ub & 0x80000000u) ? ~ub : (ub | 0x80000000u);
        unsigned long long key = ((unsigned long long)ub << 32) | (unsigned)(~bk[i]);
#pragma unroll
        for (int msk = 1; msk <= 8; msk <<= 1) {
            unsigned long long o = __shfl_xor(key, msk, 64);
            key = (o > key) ? o : key;
        }
        if (lc == 0) {
            int qt = i >> 2, r = i & 3;
            int q = qbase + qt * 16 + quad * 4 + r;   // C row = quad*4 + reg
            keys8[kc * NQ + q] = key;                 // block owns this slot
        }
    }
}

// ---------------------------------------------------------------------------
// K2: finalize. Per query: EXACT fp32 rescore of the 8 chunk winners
// (candidates ascend in idx across c -> strict '>' keeps smallest idx ==
// np argmin-first), histogram, z_q via inv_norm gather, straight-through out,
// loss. Last-done block (device-scope counter) computes entropy + loss.
// ---------------------------------------------------------------------------
__global__ __launch_bounds__(256) void finalize_kernel(const float* __restrict__ z,
                                                       const float* __restrict__ e,
                                                       const float* __restrict__ inv_norm,
                                                       const unsigned long long* __restrict__ keys8,
                                                       unsigned* __restrict__ usage,
                                                       float* __restrict__ loss_acc,
                                                       unsigned* __restrict__ done_ctr,
                                                       float* __restrict__ out) {
    int n = blockIdx.x * 256 + threadIdx.x;        // 0..NQ-1
    int b  = n >> 10;
    int hw = n & 1023;
    const float* zb = z + b * (DIM * 1024) + hw;

    float q[DIM];
    float ss = 0.f;
#pragma unroll
    for (int d = 0; d < DIM; ++d) {
        q[d] = zb[d * 1024];
        ss = fmaf(q[d], q[d], ss);
    }
    float inv = 1.f / fmaxf(sqrtf(ss), 1e-12f);
#pragma unroll
    for (int d = 0; d < DIM; ++d) q[d] *= inv;

    // ---- exact rescore of the 8 per-chunk candidates ----
    float bestd = -1e30f;
    int idx = 0;
#pragma unroll
    for (int c = 0; c < 8; ++c) {
        unsigned long long key = keys8[c * NQ + n];
        int k = (int)(~(unsigned)(key & 0xFFFFFFFFull));
        const float4* er = (const float4*)(e + k * DIM);
        float dot = 0.f;
#pragma unroll
        for (int d8 = 0; d8 < 8; ++d8) {
            float4 t4 = er[d8];
            dot = fmaf(t4.x, q[d8*4+0], dot);
            dot = fmaf(t4.y, q[d8*4+1], dot);
            dot = fmaf(t4.z, q[d8*4+2], dot);
            dot = fmaf(t4.w, q[d8*4+3], dot);
        }
        dot *= inv_norm[k];
        if (dot > bestd) { bestd = dot; idx = k; }   // candidates ascend in k
    }

    atomicAdd(&usage[idx], 1u);

    // gather winner row, normalize via table, write straight-through + loss
    float inv2 = inv_norm[idx];
    const float4* er = (const float4*)(e + idx * DIM);
    float lsum = 0.f;
    float* outb = out + b * (DIM * 1024) + hw;
#pragma unroll
    for (int d8 = 0; d8 < 8; ++d8) {
        float4 t4 = er[d8];
        float w4[4] = {t4.x, t4.y, t4.z, t4.w};
#pragma unroll
        for (int j = 0; j < 4; ++j) {
            int d = d8 * 4 + j;
            float zq = w4[j] * inv2;
            float diff = zq - q[d];
            lsum = fmaf(diff, diff, lsum);
            outb[d * 1024] = q[d] + (zq - q[d]);   // faithful to zn + sg(z_q - zn)
        }
    }
    out[IDX_OFF + n] = (float)idx;

#pragma unroll
    for (int off = 32; off > 0; off >>= 1)
        lsum += __shfl_down(lsum, off, 64);
    if ((threadIdx.x & 63) == 0)
        atomicAdd(loss_acc, lsum);

    // ---- last-done block computes the scalars ----
    __shared__ unsigned lastflag;
    __syncthreads();
    if (threadIdx.x == 0) {
        __threadfence();
        unsigned prev = __hip_atomic_fetch_add(done_ctr, 1u, __ATOMIC_ACQ_REL,
                                               __HIP_MEMORY_SCOPE_AGENT);
        lastflag = (prev == gridDim.x - 1) ? 1u : 0u;
    }
    __syncthreads();
    if (lastflag) {
        __shared__ double sm[256];
        int t = threadIdx.x;
        double local = 0.0;
        const float denom = 32768.8192f;   // sum(usage)+K*eps; sum(usage)==NQ
        for (int k = t; k < N_EMBED; k += 256) {
            unsigned c = __hip_atomic_load(&usage[k], __ATOMIC_RELAXED,
                                           __HIP_MEMORY_SCOPE_AGENT);
            float p = ((float)c + 1e-4f) / denom;
            local += (double)(-(p * logf(p)));
        }
        sm[t] = local;
        __syncthreads();
        for (int s = 128; s > 0; s >>= 1) {
            if (t < s) sm[t] += sm[t + s];
            __syncthreads();
        }
        if (t == 0) {
            float la = __hip_atomic_load(loss_acc, __ATOMIC_RELAXED,
                                         __HIP_MEMORY_SCOPE_AGENT);
            out[LOSS_OFF] = (float)(1.25 * (double)la / 32768.0);  // (beta+1)*mean
            out[ENT_OFF]  = (float)sm[0];
        }
    }
}

// ---------------------------------------------------------------------------
extern "C" void kernel_launch(void* const* d_in, const int* in_sizes, int n_in,
                              void* d_out, int out_size, void* d_ws, size_t ws_size,
                              hipStream_t stream) {
    const float* z   = (const float*)d_in[0];   // (32, 32, 32, 32) bchw
    const float* emb = (const float*)d_in[1];   // (8192, 32)
    float* out = (float*)d_out;

    char* ws = (char*)d_ws;
    half8* esplit            = (half8*)ws;                                   // 1 MiB @ 0
    unsigned long long* keys8= (unsigned long long*)(ws + (1 << 20));        // 2 MiB @ 1 MiB
    float* inv_norm          = (float*)(ws + 3 * (1 << 20));                 // 32 KiB
    unsigned* usage          = (unsigned*)(ws + 3 * (1 << 20) + 32768);      // 32 KiB
    float* loss_acc          = (float*)(ws + 3 * (1 << 20) + 65536);
    unsigned* done_ctr       = (unsigned*)(ws + 3 * (1 << 20) + 65536 + 4);

    prep_kernel<<<N_EMBED / 256, 256, 0, stream>>>(emb, esplit, inv_norm, usage,
                                                   loss_acc, done_ctr);
    score_kernel<<<NQG * KSPL, 256, 0, stream>>>(z, esplit, keys8);
    finalize_kernel<<<NQ / 256, 256, 0, stream>>>(z, emb, inv_norm, keys8, usage,
                                                  loss_acc, done_ctr, out);
}